// Round 5
// baseline (541.970 us; speedup 1.0000x reference)
//
#include <hip/hip_runtime.h>
#include <math.h>

#define TOKENS   8192
#define HIDDEN   7168
#define NEXPERT  256
#define NGROUP   8
#define TOPKG    4
#define TOPK     8
#define SCALE    2.5f

// R11: LDS-free, barrier-free register-streaming GEMM.
// R8/R9/R10 post-mortem: every LDS+barrier variant lands at 137-173 us with
// MfmaUtil pinned 21-25%. Floor arithmetic: MFMA pipe 43.5 us, LDS unit ~54 us
// -> LDS staging is the largest floor AND barriers serialize it against MFMA.
// Eliminate it: for mfma_16x16x32_f16, lane (fr,quad) needs A[row][quad*8..+7]
// = 2 contiguous float4 straight from X (wave footprint = 16 rows x 128 B,
// fully line-covered), and the B fragment is EXACTLY one hi8/lo8 half8 in the
// pre-split W image (16 B load = finished fragment). So:
//   - block = 4 waves, same 64-row M-tile, wn = wave*64 (full N=256)
//     -> X fetched once from HBM; A re-reads by 4 waves hit L1 (8 KB/tile).
//   - per wave-tile iter: cvt A (96 VALU, overlaps MFMA pipe, m114) ->
//     issue t+1 loads into ping-pong regs (counted vmcnt, never drains) ->
//     48 MFMA (16 independent acc[i][j] chains of 3).
//   - NO LDS, NO __syncthreads: waves fully decoupled, 2 waves/SIMD.
//   - KSPLIT=4 (same K-partition/order as bit-exact R8 -> absmax 0.0).
#define BM 64                   // per-block M rows (one wave-tile of M)
#define BK 32
#define KSPLIT 4
#define KPB (HIDDEN / KSPLIT)   // 1792
#define NT  (KPB / BK)          // 56
#define WTILE_BYTES 32768       // W image tile (kz,t): 256 cols x 4 oct x 32 B

typedef _Float16 half8 __attribute__((ext_vector_type(8)));
typedef float    floatx4 __attribute__((ext_vector_type(4)));

// fp32x8 -> fp16 hi/lo split (RNE; identical bits to the R6/R8-proven path).
// logit = sum al*bh + ah*bl + ah*bh in fp32 MFMA acc; dropped al*bl ~ 2^-22.
__device__ __forceinline__ void cvt8(const float4 a, const float4 b,
                                     half8& h, half8& l) {
    h[0] = (_Float16)a.x; h[1] = (_Float16)a.y;
    h[2] = (_Float16)a.z; h[3] = (_Float16)a.w;
    h[4] = (_Float16)b.x; h[5] = (_Float16)b.y;
    h[6] = (_Float16)b.z; h[7] = (_Float16)b.w;
    l[0] = (_Float16)(a.x - (float)h[0]); l[1] = (_Float16)(a.y - (float)h[1]);
    l[2] = (_Float16)(a.z - (float)h[2]); l[3] = (_Float16)(a.w - (float)h[3]);
    l[4] = (_Float16)(b.x - (float)h[4]); l[5] = (_Float16)(b.y - (float)h[5]);
    l[6] = (_Float16)(b.z - (float)h[6]); l[7] = (_Float16)(b.w - (float)h[7]);
}

// ---------------------------------------------------------------------------
// W pre-split + OUT zeroing fused. Image tile (kz,t): 256 cols x 4 k-octets
// x (hi8|lo8) = 32 KB; entry ((col*4+oct)*32) is the EXACT B-fragment pair
// the GEMM loads (16 B hi, 16 B lo). One block/expert, 896 threads.
// ---------------------------------------------------------------------------
__global__ __launch_bounds__(896) void wsplit_kernel(
    const float* __restrict__ W, char* __restrict__ WS, float* __restrict__ O)
{
    const int gt = blockIdx.x * 896 + threadIdx.x;
#pragma unroll
    for (int i = 0; i < 3; i++) {
        const int idx = gt + i * (NEXPERT * 896);
        if (idx < TOKENS * NEXPERT / 4)
            *(float4*)&O[(size_t)idx * 4] = float4{0.f, 0.f, 0.f, 0.f};
    }

    const int e  = blockIdx.x;          // expert 0..255
    const int og = threadIdx.x;         // k-octet within expert, 0..895
    const float4 a = *(const float4*)&W[(size_t)e * HIDDEN + og * 8];
    const float4 b = *(const float4*)&W[(size_t)e * HIDDEN + og * 8 + 4];
    half8 h, l;
    cvt8(a, b, h, l);

    const int kz = og / (KPB / 8);          // k-split 0..3 (448 octets per kz)
    const int tt = (og % (KPB / 8)) >> 2;   // k-tile  0..55
    const int oc = og & 3;                  // octet   0..3
    char* p = WS + (size_t)(kz * NT + tt) * WTILE_BYTES + (e * 4 + oc) * 32;
    *(half8*)p        = h;
    *(half8*)(p + 16) = l;
}

// ---------------------------------------------------------------------------
// Gate GEMM: register-streaming, per-wave independent.
// Fragment maps (16x16x32_f16, R8-proven): A/B lane (fr,quad) holds
// row/col = base + fr, k = quad*8..+7. D: row = quad*4+reg, col = fr.
// ---------------------------------------------------------------------------
__global__ __launch_bounds__(256, 2) void gate_gemm_kernel(
    const float* __restrict__ X, const char* __restrict__ WS,
    float* __restrict__ OUT)
{
    const int tid  = threadIdx.x;
    const int lane = tid & 63, wave = tid >> 6;
    const int mb   = blockIdx.x * BM;       // 128 M-tiles
    const int kz   = blockIdx.y;            // 4 K-splits
    const int wn   = wave * 64;             // wave's N-tile
    const int fr   = lane & 15, quad = lane >> 4;

    // A: lane reads X[mb + i*16 + fr][kz*KPB + t*32 + quad*8 .. +7]
    const float* Abase = X + (size_t)(mb + fr) * HIDDEN + kz * KPB + quad * 8;
    // B: lane reads image (kz,t) at col = wn + j*16 + fr, oct = quad
    const char* Bbase = WS + (size_t)(kz * NT) * WTILE_BYTES
                      + (wn + fr) * 128 + quad * 32;

    floatx4 acc[4][4];
#pragma unroll
    for (int i = 0; i < 4; i++)
#pragma unroll
        for (int j = 0; j < 4; j++) acc[i][j] = floatx4{0.f, 0.f, 0.f, 0.f};

    // ping-pong register buffers (static indexing only — rule #20)
    float4 avA[4][2], avB[4][2];
    half8  bhA[4], blA[4], bhB[4], blB[4];

    // prologue: issue tile-0 loads into buffer A
#pragma unroll
    for (int i = 0; i < 4; i++) {
        const float* ap = Abase + (size_t)(i * 16) * HIDDEN;
        avA[i][0] = *(const float4*)ap;
        avA[i][1] = *(const float4*)(ap + 4);
    }
#pragma unroll
    for (int j = 0; j < 4; j++) {
        bhA[j] = *(const half8*)(Bbase + j * 2048);
        blA[j] = *(const half8*)(Bbase + j * 2048 + 16);
    }

    // STEP: cvt A(t) from AVC; issue t+1 loads into AVN/BHN/BLN (clamped at
    // the tail -> harmless redundant reload); 48 MFMA on (AVC-derived, BHC/BLC).
    // vmcnt stays counted: cvt waits only through A(t) (B(t) issued after it),
    // first MFMA waits through B(t) (t+1 loads issued after are not waited).
#define STEP(AVC, AVN, BHC, BLC, BHN, BLN, T)                                 \
    {                                                                         \
        half8 ah[4], al[4];                                                   \
        _Pragma("unroll")                                                     \
        for (int i = 0; i < 4; i++)                                           \
            cvt8(AVC[i][0], AVC[i][1], ah[i], al[i]);                         \
        const int tn = ((T) + 1 < NT) ? (T) + 1 : NT - 1;                     \
        _Pragma("unroll")                                                     \
        for (int i = 0; i < 4; i++) {                                         \
            const float* ap = Abase + (size_t)(i * 16) * HIDDEN + tn * BK;    \
            AVN[i][0] = *(const float4*)ap;                                   \
            AVN[i][1] = *(const float4*)(ap + 4);                             \
        }                                                                     \
        const char* bp = Bbase + (size_t)tn * WTILE_BYTES;                    \
        _Pragma("unroll")                                                     \
        for (int j = 0; j < 4; j++) {                                         \
            BHN[j] = *(const half8*)(bp + j * 2048);                          \
            BLN[j] = *(const half8*)(bp + j * 2048 + 16);                     \
        }                                                                     \
        _Pragma("unroll")                                                     \
        for (int j = 0; j < 4; j++)                                           \
            _Pragma("unroll")                                                 \
            for (int i = 0; i < 4; i++) {                                     \
                acc[i][j] = __builtin_amdgcn_mfma_f32_16x16x32_f16(           \
                    al[i], BHC[j], acc[i][j], 0, 0, 0);                       \
                acc[i][j] = __builtin_amdgcn_mfma_f32_16x16x32_f16(           \
                    ah[i], BLC[j], acc[i][j], 0, 0, 0);                       \
                acc[i][j] = __builtin_amdgcn_mfma_f32_16x16x32_f16(           \
                    ah[i], BHC[j], acc[i][j], 0, 0, 0);                       \
            }                                                                 \
    }

    for (int t = 0; t < NT; t += 2) {
        STEP(avA, avB, bhA, blA, bhB, blB, t)
        STEP(avB, avA, bhB, blB, bhA, blA, t + 1)
    }
#undef STEP

    // epilogue: split-K accumulation via atomicAdd (R3/R8-proven, 4-way)
#pragma unroll
    for (int i = 0; i < 4; i++)
#pragma unroll
        for (int j = 0; j < 4; j++) {
            const int col = wn + j * 16 + fr;
#pragma unroll
            for (int r = 0; r < 4; r++) {
                const int row = mb + i * 16 + quad * 4 + r;
                atomicAdd(&OUT[(size_t)row * NEXPERT + col], acc[i][j][r]);
            }
        }
}

// ---------------------------------------------------------------------------
// Routing: one wave per token, in-place on d_out (logits -> gate weights).
// Sigmoid fused; exact jax semantics incl. lowest-index tie-breaks.
// ---------------------------------------------------------------------------
__global__ __launch_bounds__(256) void route_kernel(
    float* __restrict__ S, const float* __restrict__ bias)
{
    const int lane = threadIdx.x & 63;
    const int wave = threadIdx.x >> 6;
    const int t    = blockIdx.x * 4 + wave;

    const float4 lg4 = *(const float4*)&S[(size_t)t * NEXPERT + lane * 4];
    const float4 b4  = *(const float4*)&bias[lane * 4];
    float sc[4];
    sc[0] = 1.0f / (1.0f + expf(-lg4.x));
    sc[1] = 1.0f / (1.0f + expf(-lg4.y));
    sc[2] = 1.0f / (1.0f + expf(-lg4.z));
    sc[3] = 1.0f / (1.0f + expf(-lg4.w));
    float swb[4] = { sc[0] + b4.x, sc[1] + b4.y, sc[2] + b4.z, sc[3] + b4.w };

    // per-lane top-2 of 4
    float m1 = -INFINITY, m2 = -INFINITY;
#pragma unroll
    for (int j = 0; j < 4; j++) {
        const float v = swb[j];
        if (v > m1)      { m2 = m1; m1 = v; }
        else if (v > m2) { m2 = v; }
    }
    // merge across the 8 lanes of my group
#pragma unroll
    for (int s = 1; s < 8; s <<= 1) {
        const float o1 = __shfl_xor(m1, s, 64);
        const float o2 = __shfl_xor(m2, s, 64);
        const float hi = fmaxf(m1, o1);
        const float lo = fminf(m1, o1);
        m2 = fmaxf(lo, fmaxf(m2, o2));
        m1 = hi;
    }
    const float gs = m1 + m2;

    // top-4 groups by rank (tie -> lower group index)
    float gsc[NGROUP];
#pragma unroll
    for (int g = 0; g < NGROUP; g++) gsc[g] = __shfl(gs, g * 8, 64);
    const int myg = lane >> 3;
    int rank = 0;
#pragma unroll
    for (int g = 0; g < NGROUP; g++)
        rank += (gsc[g] > gs) || (gsc[g] == gs && g < myg);
    const bool kept = (rank < TOPKG);

    float v[4];
#pragma unroll
    for (int j = 0; j < 4; j++) v[j] = kept ? swb[j] : 0.0f;

    // top-8 experts: 8 rounds of wave argmax (lowest idx on ties)
    float sum = 0.0f;
    int selmask = 0;
    for (int r = 0; r < TOPK; r++) {
        float bv = -INFINITY;
        int   bi = 0x7fffffff;
#pragma unroll
        for (int j = 0; j < 4; j++) {
            const bool avail = ((selmask >> j) & 1) == 0;
            if (avail && v[j] > bv) { bv = v[j]; bi = lane * 4 + j; }
        }
#pragma unroll
        for (int s = 1; s < 64; s <<= 1) {
            const float ov = __shfl_xor(bv, s, 64);
            const int   oi = __shfl_xor(bi, s, 64);
            if (ov > bv || (ov == bv && oi < bi)) { bv = ov; bi = oi; }
        }
        const int wl = bi >> 2, wj = bi & 3;
        const float mysc = (wj == 0) ? sc[0] : (wj == 1) ? sc[1]
                         : (wj == 2) ? sc[2] : sc[3];
        sum += __shfl(mysc, wl, 64);
        if (lane == wl) selmask |= (1 << wj);
    }

    const float rcp = SCALE / (sum + 1e-20f);
    float4 o;
    o.x = (selmask & 1) ? sc[0] * rcp : 0.0f;
    o.y = (selmask & 2) ? sc[1] * rcp : 0.0f;
    o.z = (selmask & 4) ? sc[2] * rcp : 0.0f;
    o.w = (selmask & 8) ? sc[3] * rcp : 0.0f;
    *(float4*)&S[(size_t)t * NEXPERT + lane * 4] = o;
}

extern "C" void kernel_launch(void* const* d_in, const int* in_sizes, int n_in,
                              void* d_out, int out_size, void* d_ws, size_t ws_size,
                              hipStream_t stream) {
    const float* X    = (const float*)d_in[0];   // [8192, 7168]
    const float* W    = (const float*)d_in[1];   // [256, 7168]
    const float* bias = (const float*)d_in[2];   // [256]
    float* out = (float*)d_out;                  // [8192, 256]
    // d_ws: 4*56 tiles x 32 KB = 7,340,032 B of pre-split W-fragment images.
    // Harness poison-fills d_ws every iteration regardless of use (R0-R2
    // evidence) -> using it is free; we rewrite our slice before the GEMM.
    char* ws = (char*)d_ws; (void)ws_size;

    wsplit_kernel<<<NEXPERT, 896, 0, stream>>>(W, ws, out);
    dim3 ggrid(TOKENS / BM, KSPLIT);             // (128, 4) = 512 blocks
    gate_gemm_kernel<<<ggrid, 256, 0, stream>>>(X, ws, out);
    route_kernel<<<TOKENS / 4, 256, 0, stream>>>(out, bias);
}

// Round 6
// 426.339 us; speedup vs baseline: 1.2712x; 1.2712x over previous
//
#include <hip/hip_runtime.h>
#include <math.h>

#define TOKENS   8192
#define HIDDEN   7168
#define NEXPERT  256
#define NGROUP   8
#define TOPKG    4
#define TOPK     8
#define SCALE    2.5f

// R12: hybrid staging. Map of the space (gemm us): R8 dbuf-LDS 2blk/CU=137,
// R10 single-buf 4blk/CU=152, R9 phased 1blk/CU=173, R11 no-LDS 2blk/CU=300.
// Constraints learned: need (a) dbuf staging overlapping MFMA, (b) >=3
// independent blocks/CU, (c) register-destined global loads (no vmcnt drain
// at barriers), (d) independent MFMA chains. R8 = a,c,d but 72 KB LDS caps
// (b). Fix: B needs NO LDS at all — the pre-split W image delivers finished
// B fragments as single 16 B loads (R11-proven numerics). A-only dbuf LDS =
// 18 KB/block; VGPR (~160, bounds(256,3)) caps 3 blocks/CU; grid 1024.
//   block: 256 thr, 4 waves, BM=64 (shared by all waves), BN=256 (wn=wave*64)
//   per tile, ONE barrier: issue B(t) frags -> cvt+stage A(t) (regs from
//   prev tile; counted vmcnt, B stays in flight) -> issue A(t+1) -> barrier
//   -> 8 A-frag ds_reads -> 48 MFMA (B-wait counted, covered by stage+
//   barrier+reads; A(t+1) un-waited).
// LDS traffic halves vs R8; staging VALU halves; B re-reads hit L2
// (0.92 MB/kz slice). KSPLIT=8 (absmax 0.00195 precedent passed R9/R10).
#define BM 64
#define BK 32
#define KSPLIT 8
#define KPB (HIDDEN / KSPLIT)   // 896
#define NT  (KPB / BK)          // 28
#define WTILE_BYTES 32768       // W image tile (kz,t): 256 cols x 4 oct x 32 B

// A LDS layout (halves): addr(row,k,hl) = row*72 + (k>>3)*16 + hl*8 + (k&7).
// Row stride 144 B -> frag-read start banks cycle with period 8, <=2-way
// aliasing (R8-proven free). 64 x 72 x 2 B = 9 KB per buffer, dbuf 18 KB.
#define RSTR 72

typedef _Float16 half8 __attribute__((ext_vector_type(8)));
typedef float    floatx4 __attribute__((ext_vector_type(4)));

// fp32x8 -> fp16 hi/lo split (RNE; identical bits to the R6/R8-proven path).
// logit = sum al*bh + ah*bl + ah*bh in fp32 MFMA acc; dropped al*bl ~ 2^-22.
__device__ __forceinline__ void cvt8(const float4 a, const float4 b,
                                     half8& h, half8& l) {
    h[0] = (_Float16)a.x; h[1] = (_Float16)a.y;
    h[2] = (_Float16)a.z; h[3] = (_Float16)a.w;
    h[4] = (_Float16)b.x; h[5] = (_Float16)b.y;
    h[6] = (_Float16)b.z; h[7] = (_Float16)b.w;
    l[0] = (_Float16)(a.x - (float)h[0]); l[1] = (_Float16)(a.y - (float)h[1]);
    l[2] = (_Float16)(a.z - (float)h[2]); l[3] = (_Float16)(a.w - (float)h[3]);
    l[4] = (_Float16)(b.x - (float)h[4]); l[5] = (_Float16)(b.y - (float)h[5]);
    l[6] = (_Float16)(b.z - (float)h[6]); l[7] = (_Float16)(b.w - (float)h[7]);
}

// ---------------------------------------------------------------------------
// W pre-split + OUT zeroing fused. Image tile (kz,t): 256 cols x 4 k-octets
// x (hi8|lo8) = 32 KB; entry ((col*4+oct)*32) is the EXACT B-fragment pair
// the GEMM loads (16 B hi, 16 B lo). One block/expert, 896 threads.
// ---------------------------------------------------------------------------
__global__ __launch_bounds__(896) void wsplit_kernel(
    const float* __restrict__ W, char* __restrict__ WS, float* __restrict__ O)
{
    const int gt = blockIdx.x * 896 + threadIdx.x;
#pragma unroll
    for (int i = 0; i < 3; i++) {
        const int idx = gt + i * (NEXPERT * 896);
        if (idx < TOKENS * NEXPERT / 4)
            *(float4*)&O[(size_t)idx * 4] = float4{0.f, 0.f, 0.f, 0.f};
    }

    const int e  = blockIdx.x;          // expert 0..255
    const int og = threadIdx.x;         // k-octet within expert, 0..895
    const float4 a = *(const float4*)&W[(size_t)e * HIDDEN + og * 8];
    const float4 b = *(const float4*)&W[(size_t)e * HIDDEN + og * 8 + 4];
    half8 h, l;
    cvt8(a, b, h, l);

    const int kz = og / (KPB / 8);          // k-split 0..7 (112 octets per kz)
    const int tt = (og % (KPB / 8)) >> 2;   // k-tile  0..27
    const int oc = og & 3;                  // octet   0..3
    char* p = WS + (size_t)(kz * NT + tt) * WTILE_BYTES + (e * 4 + oc) * 32;
    *(half8*)p        = h;
    *(half8*)(p + 16) = l;
}

// ---------------------------------------------------------------------------
// Gate GEMM. Fragment maps (16x16x32_f16, R8-proven): A/B lane (fr,quad)
// holds row/col = base + fr, k = quad*8..+7. D: row = quad*4+reg, col = fr.
// ---------------------------------------------------------------------------
__global__ __launch_bounds__(256, 3) void gate_gemm_kernel(
    const float* __restrict__ X, const char* __restrict__ WS,
    float* __restrict__ OUT)
{
    __shared__ _Float16 Ab[2][BM * RSTR];   // 2 x 9 KB = 18 KB total

    const int tid = threadIdx.x;
    const int mb  = blockIdx.x * BM;        // 128 M-blocks
    const int kz  = blockIdx.y;             // 8 K-splits

    // A staging: thread -> (row = tid>>2 in 0..63, octet = tid&3); one
    // k-octet (2 float4) per thread per tile; hi/lo half8 pair into LDS.
    const int arow = tid >> 2, aoct = tid & 3;
    const float* Aptr = X + (size_t)(mb + arow) * HIDDEN + kz * KPB + aoct * 8;
    const int alb = arow * RSTR + aoct * 16;

    const int lane = tid & 63, wave = tid >> 6;
    const int wn   = wave * 64;             // wave's N-tile (full N covered)
    const int fr   = lane & 15, quad = lane >> 4;

    // B: lane loads image (kz,t) at col = wn + j*16 + fr, oct = quad;
    // 16 B hi at +0, 16 B lo at +16 — finished MFMA fragments.
    const char* Bbase = WS + (size_t)(kz * NT) * WTILE_BYTES
                      + (wn + fr) * 128 + quad * 32;

    floatx4 acc[4][4];
#pragma unroll
    for (int i = 0; i < 4; i++)
#pragma unroll
        for (int j = 0; j < 4; j++) acc[i][j] = floatx4{0.f, 0.f, 0.f, 0.f};

    // prologue: issue A(0) loads (register-destined)
    float4 av0 = *(const float4*)Aptr;
    float4 av1 = *(const float4*)(Aptr + 4);

    for (int t = 0; t < NT; t++) {
        // 1) issue B(t) fragment loads (newest in queue; stage's A-wait
        //    below is a counted vmcnt that leaves these in flight)
        const char* bp = Bbase + (size_t)t * WTILE_BYTES;
        half8 bh[4], bl[4];
#pragma unroll
        for (int j = 0; j < 4; j++) {
            bh[j] = *(const half8*)(bp + j * 2048);
            bl[j] = *(const half8*)(bp + j * 2048 + 16);
        }

        // 2) cvt + stage A(t) into buf[t&1] (waits on A(t) loads only —
        //    issued one full tile ago)
        {
            half8 ha, la;
            cvt8(av0, av1, ha, la);
            _Float16* An = Ab[t & 1];
            *(half8*)&An[alb]     = ha;
            *(half8*)&An[alb + 8] = la;
        }

        // 3) issue A(t+1) loads (clamped tail -> harmless redundant reload)
        {
            const int tn = (t + 1 < NT) ? t + 1 : NT - 1;
            const float* ap = Aptr + tn * BK;
            av0 = *(const float4*)ap;
            av1 = *(const float4*)(ap + 4);
        }

        // 4) one barrier per tile: buf[t&1] staged; dbuf rotation makes the
        //    read-vs-next-write hazard safe with a single barrier (R8-style)
        __syncthreads();

        // 5) A-frag reads from buf[t&1]
        const _Float16* Ac = Ab[t & 1];
        half8 ah[4], al[4];
#pragma unroll
        for (int i = 0; i < 4; i++) {
            const int a = (i * 16 + fr) * RSTR + quad * 16;
            ah[i] = *(const half8*)&Ac[a];
            al[i] = *(const half8*)&Ac[a + 8];
        }

        // 6) 48 MFMA, 16 independent acc chains; first MFMA's B-wait is a
        //    counted vmcnt (A(t+1) issued after B(t) stays in flight)
#pragma unroll
        for (int j = 0; j < 4; j++)
#pragma unroll
            for (int i = 0; i < 4; i++) {
                acc[i][j] = __builtin_amdgcn_mfma_f32_16x16x32_f16(
                    al[i], bh[j], acc[i][j], 0, 0, 0);
                acc[i][j] = __builtin_amdgcn_mfma_f32_16x16x32_f16(
                    ah[i], bl[j], acc[i][j], 0, 0, 0);
                acc[i][j] = __builtin_amdgcn_mfma_f32_16x16x32_f16(
                    ah[i], bh[j], acc[i][j], 0, 0, 0);
            }
    }

    // epilogue: D row = token (quad*4+reg), col = expert (fr);
    // split-K accumulation via atomicAdd (R3/R8-proven pattern, 8-way)
#pragma unroll
    for (int i = 0; i < 4; i++)
#pragma unroll
        for (int j = 0; j < 4; j++) {
            const int col = wn + j * 16 + fr;
#pragma unroll
            for (int r = 0; r < 4; r++) {
                const int row = mb + i * 16 + quad * 4 + r;
                atomicAdd(&OUT[(size_t)row * NEXPERT + col], acc[i][j][r]);
            }
        }
}

// ---------------------------------------------------------------------------
// Routing: one wave per token, in-place on d_out (logits -> gate weights).
// Sigmoid fused; exact jax semantics incl. lowest-index tie-breaks.
// ---------------------------------------------------------------------------
__global__ __launch_bounds__(256) void route_kernel(
    float* __restrict__ S, const float* __restrict__ bias)
{
    const int lane = threadIdx.x & 63;
    const int wave = threadIdx.x >> 6;
    const int t    = blockIdx.x * 4 + wave;

    const float4 lg4 = *(const float4*)&S[(size_t)t * NEXPERT + lane * 4];
    const float4 b4  = *(const float4*)&bias[lane * 4];
    float sc[4];
    sc[0] = 1.0f / (1.0f + expf(-lg4.x));
    sc[1] = 1.0f / (1.0f + expf(-lg4.y));
    sc[2] = 1.0f / (1.0f + expf(-lg4.z));
    sc[3] = 1.0f / (1.0f + expf(-lg4.w));
    float swb[4] = { sc[0] + b4.x, sc[1] + b4.y, sc[2] + b4.z, sc[3] + b4.w };

    // per-lane top-2 of 4
    float m1 = -INFINITY, m2 = -INFINITY;
#pragma unroll
    for (int j = 0; j < 4; j++) {
        const float v = swb[j];
        if (v > m1)      { m2 = m1; m1 = v; }
        else if (v > m2) { m2 = v; }
    }
    // merge across the 8 lanes of my group
#pragma unroll
    for (int s = 1; s < 8; s <<= 1) {
        const float o1 = __shfl_xor(m1, s, 64);
        const float o2 = __shfl_xor(m2, s, 64);
        const float hi = fmaxf(m1, o1);
        const float lo = fminf(m1, o1);
        m2 = fmaxf(lo, fmaxf(m2, o2));
        m1 = hi;
    }
    const float gs = m1 + m2;

    // top-4 groups by rank (tie -> lower group index)
    float gsc[NGROUP];
#pragma unroll
    for (int g = 0; g < NGROUP; g++) gsc[g] = __shfl(gs, g * 8, 64);
    const int myg = lane >> 3;
    int rank = 0;
#pragma unroll
    for (int g = 0; g < NGROUP; g++)
        rank += (gsc[g] > gs) || (gsc[g] == gs && g < myg);
    const bool kept = (rank < TOPKG);

    float v[4];
#pragma unroll
    for (int j = 0; j < 4; j++) v[j] = kept ? swb[j] : 0.0f;

    // top-8 experts: 8 rounds of wave argmax (lowest idx on ties)
    float sum = 0.0f;
    int selmask = 0;
    for (int r = 0; r < TOPK; r++) {
        float bv = -INFINITY;
        int   bi = 0x7fffffff;
#pragma unroll
        for (int j = 0; j < 4; j++) {
            const bool avail = ((selmask >> j) & 1) == 0;
            if (avail && v[j] > bv) { bv = v[j]; bi = lane * 4 + j; }
        }
#pragma unroll
        for (int s = 1; s < 64; s <<= 1) {
            const float ov = __shfl_xor(bv, s, 64);
            const int   oi = __shfl_xor(bi, s, 64);
            if (ov > bv || (ov == bv && oi < bi)) { bv = ov; bi = oi; }
        }
        const int wl = bi >> 2, wj = bi & 3;
        const float mysc = (wj == 0) ? sc[0] : (wj == 1) ? sc[1]
                         : (wj == 2) ? sc[2] : sc[3];
        sum += __shfl(mysc, wl, 64);
        if (lane == wl) selmask |= (1 << wj);
    }

    const float rcp = SCALE / (sum + 1e-20f);
    float4 o;
    o.x = (selmask & 1) ? sc[0] * rcp : 0.0f;
    o.y = (selmask & 2) ? sc[1] * rcp : 0.0f;
    o.z = (selmask & 4) ? sc[2] * rcp : 0.0f;
    o.w = (selmask & 8) ? sc[3] * rcp : 0.0f;
    *(float4*)&S[(size_t)t * NEXPERT + lane * 4] = o;
}

extern "C" void kernel_launch(void* const* d_in, const int* in_sizes, int n_in,
                              void* d_out, int out_size, void* d_ws, size_t ws_size,
                              hipStream_t stream) {
    const float* X    = (const float*)d_in[0];   // [8192, 7168]
    const float* W    = (const float*)d_in[1];   // [256, 7168]
    const float* bias = (const float*)d_in[2];   // [256]
    float* out = (float*)d_out;                  // [8192, 256]
    // d_ws: 8*28 tiles x 32 KB = 7,340,032 B of pre-split W-fragment images.
    // Harness poison-fills d_ws every iteration regardless of use (R0-R2
    // evidence) -> using it is free; we rewrite our slice before the GEMM.
    char* ws = (char*)d_ws; (void)ws_size;

    wsplit_kernel<<<NEXPERT, 896, 0, stream>>>(W, ws, out);
    dim3 ggrid(TOKENS / BM, KSPLIT);             // (128, 8) = 1024 blocks
    gate_gemm_kernel<<<ggrid, 256, 0, stream>>>(X, ws, out);
    route_kernel<<<TOKENS / 4, 256, 0, stream>>>(out, bias);
}